// Round 3
// baseline (83.075 us; speedup 1.0000x reference)
//
#include <hip/hip_runtime.h>
#include <hip/hip_bf16.h>

// QuantumKANLayer: S = [cos|sin features](32768x4096) @ W(4096x256), bf16 MFMA.
// R2: 32x32x16 MFMA (4061 FLOP/cyc/CU ceiling), conflict-free A-tile layout
//     (k reordered as h*64+i*8+kk within each 128-k step; W packed to match),
//     B-fragments direct from L2 (fragment-major), scalar casts for bf16.

#define BM 64
#define NST 32           // 4096 / 128

typedef __attribute__((ext_vector_type(8)))  short short8;
typedef __attribute__((ext_vector_type(16))) float f32x16;

static __device__ __forceinline__ unsigned short f2bf(float f) {
    union { float f; unsigned u; } v; v.f = f;
    unsigned r = v.u + 0x7fff + ((v.u >> 16) & 1);   // RNE
    return (unsigned short)(r >> 16);
}

// ---- pack W^T fragment-major for 32x32x16 B-frags -------------------------
// flat idx = (((s*8 + t)*8 + cg)*64 + l), 16B per idx.
// element e: h=t>>2, i=s*8+(t&3)*2+(l>>5), j=cg*32+(l&31),
//            val = (h ? coef_b : coef_a)[j][i][e]
__global__ __launch_bounds__(256) void pack_w_kernel(
        const float* __restrict__ ca, const float* __restrict__ cb,
        unsigned short* __restrict__ wt) {
    int idx = blockIdx.x * 256 + threadIdx.x;   // 131072
    int l  = idx & 63;
    int cg = (idx >> 6) & 7;
    int t  = (idx >> 9) & 7;
    int s  = idx >> 12;
    int h  = t >> 2;
    int i  = s * 8 + (t & 3) * 2 + (l >> 5);
    int j  = cg * 32 + (l & 31);
    const float* src = (h ? cb : ca) + ((size_t)j * 256 + i) * 8;
    float4 v0 = ((const float4*)src)[0];
    float4 v1 = ((const float4*)src)[1];
    alignas(16) unsigned short o[8];
    o[0] = f2bf(v0.x); o[1] = f2bf(v0.y); o[2] = f2bf(v0.z); o[3] = f2bf(v0.w);
    o[4] = f2bf(v1.x); o[5] = f2bf(v1.y); o[6] = f2bf(v1.z); o[7] = f2bf(v1.w);
    *(short8*)(wt + (size_t)idx * 8) = *(short8*)o;
}

// ---- fused feature-gen + GEMM --------------------------------------------
// 512 threads = 8 waves; wave w -> rows bm0..+63, cols w*32..+31, acc[2] 32x32.
// A tile [64 rows][16 granules x 16B] dbuf; logical granule G (cos: fi,
// sin: 8+fi) stored at physical P = G ^ (row&15)  -> conflict-free write+read.
template<bool PACKED>
__global__ __launch_bounds__(512, 4) void kan_gemm(
        const float* __restrict__ x,
        const unsigned short* __restrict__ bwt,
        const float* __restrict__ ca, const float* __restrict__ cb,
        float* __restrict__ out) {
    __shared__ __align__(16) char Alds[2][16384];

    const int tid  = threadIdx.x;
    const int l    = tid & 63;
    const int w    = tid >> 6;
    const int bm0  = blockIdx.x * BM;
    const int frow = tid >> 3;      // 0..63
    const int fi   = tid & 7;       // 0..7
    const int fswz = frow & 15;
    const int lrow = l & 31;
    const int lhalf = l >> 5;

    f32x16 acc[2];
#pragma unroll
    for (int m = 0; m < 2; ++m)
#pragma unroll
        for (int r = 0; r < 16; ++r) acc[m][r] = 0.0f;

    auto xload = [&](int s) {
        return x[(size_t)(bm0 + frow) * 256 + (size_t)(s * 8 + fi)];
    };

    auto stageA = [&](int buf, float xv) {
        float s1, c1;
        __sincosf(xv, &s1, &c1);
        __hip_bfloat16 fc[8], fs[8];
        fc[0] = __float2bfloat16(c1); fs[0] = __float2bfloat16(s1);
        const float tc = c1 + c1;
        float cp2 = 1.0f, cp1 = c1, sp2 = 0.0f, sp1 = s1;
#pragma unroll
        for (int k = 1; k < 8; ++k) {
            float cn = tc * cp1 - cp2;
            float sn = tc * sp1 - sp2;
            cp2 = cp1; cp1 = cn; sp2 = sp1; sp1 = sn;
            fc[k] = __float2bfloat16(cn); fs[k] = __float2bfloat16(sn);
        }
        char* base = Alds[buf] + frow * 256;
        *(short8*)(base + ((fi       ^ fswz) * 16)) = *(short8*)fc;
        *(short8*)(base + (((8 + fi) ^ fswz) * 16)) = *(short8*)fs;
    };

    auto loadB = [&](int s, int t) -> short8 {
        if (PACKED) {
            return *(const short8*)(bwt
                + ((size_t)(((s * 8 + t) * 8 + w) * 64 + l)) * 8);
        } else {
            const int h = t >> 2;
            const int i = s * 8 + (t & 3) * 2 + lhalf;
            const int j = w * 32 + lrow;
            const float* src = (h ? cb : ca) + ((size_t)j * 256 + i) * 8;
            float4 v0 = ((const float4*)src)[0];
            float4 v1 = ((const float4*)src)[1];
            alignas(16) unsigned short o[8];
            o[0] = f2bf(v0.x); o[1] = f2bf(v0.y);
            o[2] = f2bf(v0.z); o[3] = f2bf(v0.w);
            o[4] = f2bf(v1.x); o[5] = f2bf(v1.y);
            o[6] = f2bf(v1.z); o[7] = f2bf(v1.w);
            return *(short8*)o;
        }
    };

    // prologue
    float xv = xload(0);
    stageA(0, xv);
    float xn = xload(1);
    __syncthreads();

#pragma unroll 1
    for (int s = 0; s < NST; ++s) {
        const int buf = s & 1;

        short8 b0[4];
#pragma unroll
        for (int t = 0; t < 4; ++t) b0[t] = loadB(s, t);

        if (s + 1 < NST) stageA(buf ^ 1, xn);
        if (s + 2 < NST) xn = xload(s + 2);

        short8 b1[4];
#pragma unroll
        for (int t = 0; t < 4; ++t) b1[t] = loadB(s, 4 + t);

#pragma unroll
        for (int t = 0; t < 8; ++t) {
            const short8 bf = (t < 4) ? b0[t & 3] : b1[t & 3];
#pragma unroll
            for (int m = 0; m < 2; ++m) {
                const int row = m * 32 + lrow;
                const int P = (2 * t + lhalf) ^ (row & 15);
                const short8 af = *(const short8*)(Alds[buf] + row * 256 + P * 16);
                acc[m] = __builtin_amdgcn_mfma_f32_32x32x16_bf16(
                    af, bf, acc[m], 0, 0, 0);
            }
        }
        __syncthreads();
    }

    // epilogue: 32x32 C/D layout: col = lane&31, row = (r&3)+8*(r>>2)+4*lhalf
    const int col = w * 32 + lrow;
#pragma unroll
    for (int m = 0; m < 2; ++m)
#pragma unroll
        for (int r = 0; r < 16; ++r) {
            const int row = bm0 + m * 32 + (r & 3) + 8 * (r >> 2) + 4 * lhalf;
            out[(size_t)row * 256 + col] = acc[m][r];
        }
}

extern "C" void kernel_launch(void* const* d_in, const int* in_sizes, int n_in,
                              void* d_out, int out_size, void* d_ws, size_t ws_size,
                              hipStream_t stream) {
    const float* x  = (const float*)d_in[0];
    const float* ca = (const float*)d_in[1];
    const float* cb = (const float*)d_in[2];
    float* out = (float*)d_out;

    const size_t wt_bytes = (size_t)131072 * 16;   // 2 MiB

    if (ws_size >= wt_bytes) {
        unsigned short* wt = (unsigned short*)d_ws;
        pack_w_kernel<<<512, 256, 0, stream>>>(ca, cb, wt);
        kan_gemm<true><<<512, 512, 0, stream>>>(x, wt, ca, cb, out);
    } else {
        kan_gemm<false><<<512, 512, 0, stream>>>(x, nullptr, ca, cb, out);
    }
}